// Round 4
// baseline (98.384 us; speedup 1.0000x reference)
//
#include <hip/hip_runtime.h>

typedef __attribute__((ext_vector_type(8))) short short8;
typedef __attribute__((ext_vector_type(4))) short short4v;
typedef __attribute__((ext_vector_type(4))) float f32x4;

#define MFMA_16x16x32_BF16(A, B, C) __builtin_amdgcn_mfma_f32_16x16x32_bf16(A, B, C, 0, 0, 0)

// float -> bf16 bits, round-to-nearest-even (inputs always finite here)
__device__ __forceinline__ unsigned short f2bf(float x) {
    unsigned int u = __builtin_bit_cast(unsigned int, x);
    u = (u + 0x7FFFu + ((u >> 16) & 1u)) >> 16;
    return (unsigned short)u;
}

// ---------------------------------------------------------------------------
// Kernel 1: pack Wk|Wq|Wv (fp32 [1024][64]) -> Wt bf16 [192][1024] (transposed)
// ---------------------------------------------------------------------------
__global__ __launch_bounds__(256) void wconv_kernel(const float* __restrict__ Wk,
                                                    const float* __restrict__ Wq,
                                                    const float* __restrict__ Wv,
                                                    unsigned short* __restrict__ Wt) {
    const int n = blockIdx.x;                       // 0..191
    const float* W = (n < 64) ? Wk : (n < 128) ? Wq : Wv;
    const int col = n & 63;
    for (int k = threadIdx.x; k < 1024; k += 256)
        Wt[(size_t)n * 1024 + k] = f2bf(W[(size_t)k * 64 + col]);
}

// ---------------------------------------------------------------------------
// Kernel 2: QKV projection, streaming no-LDS no-barrier GEMM, v3.
// Grid (2, 1024) x 64 thr: block (ch, rt) computes rows 16*rt.., cols 96*ch..
// 2048 waves = 2/SIMD (TLP) on top of in-register pipelining:
//   A ring 4-deep (HBM ~900cy), B ring 2-deep (L2 ~250cy), k-loop unrolled x4
//   so all ring indices are compile-time.  Per step s:
//   [convert A(s)] [issue A(s+4)] [MFMA x6 with B(s)] [issue B(s+2)]
// Outputs: Kb/Qb row-major [16384][64]; V transposed per batch Vtg[b][64][2048].
// ---------------------------------------------------------------------------
__global__ __launch_bounds__(64) void proj_kernel(const float* __restrict__ X,
                                                  const unsigned short* __restrict__ Wt,
                                                  unsigned short* __restrict__ Kb,
                                                  unsigned short* __restrict__ Qb,
                                                  unsigned short* __restrict__ Vtg) {
    const int lane = threadIdx.x;
    const int lr = lane & 15, g = lane >> 4;
    const int ch = blockIdx.x, rt = blockIdx.y;
    const int r0 = rt * 16;
    const int n0 = ch * 96;

    f32x4 acc[6] = {};
    float4 arA[4][2];        // A ring [slot][half] — static indices only
    short8 brB[2][6];        // B ring [slot][coltile]

    const float* xb = X + (size_t)(r0 + lr) * 1024 + 8 * g;
    const unsigned short* wb = Wt + (size_t)(n0 + lr) * 1024 + 8 * g;

#define ISSUEA(SLOT, K)                                                  \
    { arA[SLOT][0] = *(const float4*)(xb + (K));                         \
      arA[SLOT][1] = *(const float4*)(xb + (K) + 4); }
#define ISSUEB(SLOT, K)                                                  \
    { _Pragma("unroll")                                                  \
      for (int c = 0; c < 6; ++c)                                        \
          brB[SLOT][c] = *(const short8*)(wb + (size_t)c * 16 * 1024 + (K)); }

    ISSUEA(0, 0) ISSUEA(1, 32) ISSUEA(2, 64) ISSUEA(3, 96)
    ISSUEB(0, 0) ISSUEB(1, 32)

#define PSTEP(S)                                                         \
    {                                                                    \
        const int k0 = (S) * 32;                                         \
        short8 af;                                                       \
        {                                                                \
            float4 v0 = arA[(S) & 3][0], v1 = arA[(S) & 3][1];           \
            af[0] = (short)f2bf(v0.x); af[1] = (short)f2bf(v0.y);        \
            af[2] = (short)f2bf(v0.z); af[3] = (short)f2bf(v0.w);        \
            af[4] = (short)f2bf(v1.x); af[5] = (short)f2bf(v1.y);        \
            af[6] = (short)f2bf(v1.z); af[7] = (short)f2bf(v1.w);        \
        }                                                                \
        if (k0 + 128 < 1024) ISSUEA((S) & 3, k0 + 128)                   \
        _Pragma("unroll")                                                \
        for (int c = 0; c < 6; ++c)                                      \
            acc[c] = MFMA_16x16x32_BF16(af, brB[(S) & 1][c], acc[c]);    \
        if (k0 + 64 < 1024) ISSUEB((S) & 1, k0 + 64)                     \
    }

    for (int j = 0; j < 8; ++j) {
        PSTEP(4 * j) PSTEP(4 * j + 1) PSTEP(4 * j + 2) PSTEP(4 * j + 3)
    }
#undef PSTEP
#undef ISSUEB
#undef ISSUEA

    // ---- epilogue: C/D layout col = lane&15 (W-col), row = 4*(lane>>4)+reg ----
    const int bb = r0 >> 11;             // batch
    const int sb0 = r0 & 2047;           // s within batch
    const int row = r0 + 4 * g;
#pragma unroll
    for (int c = 0; c < 6; ++c) {
        const int cg = 6 * ch + c;       // global col-tile 0..11
        if (cg < 4) {
#pragma unroll
            for (int r = 0; r < 4; ++r)
                Kb[(size_t)(row + r) * 64 + 16 * cg + lr] = f2bf(acc[c][r]);
        } else if (cg < 8) {
#pragma unroll
            for (int r = 0; r < 4; ++r)
                Qb[(size_t)(row + r) * 64 + 16 * (cg - 4) + lr] = f2bf(acc[c][r]);
        } else {
            const int h = 16 * (cg - 8) + lr;
            uint2 e;
            e.x = (unsigned)f2bf(acc[c][0]) | ((unsigned)f2bf(acc[c][1]) << 16);
            e.y = (unsigned)f2bf(acc[c][2]) | ((unsigned)f2bf(acc[c][3]) << 16);
            *(uint2*)(Vtg + (size_t)bb * 64 * 2048 + (size_t)h * 2048 + sb0 + 4 * g) = e;
        }
    }
}

// ---------------------------------------------------------------------------
// Kernel 3: causal flash attention, band-pair blocks, K/V software-pipelined.
// Block = bands {63-p (hi), p (lo)} of 32 q-rows each -> exactly 65 kv-steps
// per block.  8 waves split the 65 steps contiguously (linear step index
// crosses the hi->lo band boundary; wave-uniform branch selects band state).
// K/V fragments for step s+1 are issued before computing step s, hiding
// L2/L3 latency.  Partials merged in LDS at the end.
// ---------------------------------------------------------------------------
__global__ __launch_bounds__(512, 2) void attn_kernel(const unsigned short* __restrict__ Kb,
                                                      const unsigned short* __restrict__ Qb,
                                                      const unsigned short* __restrict__ Vtg,
                                                      float* __restrict__ out) {
    __shared__ __attribute__((aligned(16))) float Pacc[16][32][68];  // [slot][q][h] pad 68
    __shared__ float Pml[2][16][32];                                 // m / l per slot,q

    const int t = threadIdx.x;
    const int w = t >> 6, lane = t & 63;
    const int lr = lane & 15, g = lane >> 4;
    const int p = blockIdx.x, b = blockIdx.y;
    const int nhi = 64 - p;                      // steps for hi band
    const int q0h = (63 - p) * 32, q0l = p * 32;
    const size_t rowbase = (size_t)b * 2048;
    const size_t vbase = (size_t)b * 64 * 2048;
    const float NEG_INF = -__builtin_inff();
    const float SCALE2 = 0.03125f * 1.4426950408889634f;   // d^-0.5 * log2(e)

    // Q fragments (B-operand): [sub][hh]
    short8 qfH[2][2], qfL[2][2];
#pragma unroll
    for (int sub = 0; sub < 2; ++sub)
#pragma unroll
        for (int hh = 0; hh < 2; ++hh) {
            qfH[sub][hh] = *(const short8*)(Qb + (rowbase + q0h + 16 * sub + lr) * 64 + 32 * hh + 8 * g);
            qfL[sub][hh] = *(const short8*)(Qb + (rowbase + q0l + 16 * sub + lr) * 64 + 32 * hh + 8 * g);
        }

    f32x4 accH[2][4] = {}, accL[2][4] = {};
    float mH[2] = {NEG_INF, NEG_INF}, mL[2] = {NEG_INF, NEG_INF};
    float lH[2] = {0.f, 0.f}, lL[2] = {0.f, 0.f};

    const int s0 = (w * 65) >> 3, s1 = ((w + 1) * 65) >> 3;

    auto loadKV = [&](int kv0, short8 (&kf)[2][2], short8 (&vf)[4]) {
#pragma unroll
        for (int f = 0; f < 2; ++f)
#pragma unroll
            for (int hh = 0; hh < 2; ++hh)
                kf[f][hh] = *(const short8*)(Kb + (rowbase + kv0 + 16 * f + lr) * 64 + 32 * hh + 8 * g);
#pragma unroll
        for (int fh = 0; fh < 4; ++fh) {
            const unsigned short* vp = Vtg + vbase + (size_t)(16 * fh + lr) * 2048 + kv0 + 4 * g;
            short4v v0 = *(const short4v*)vp;
            short4v v1 = *(const short4v*)(vp + 16);
            short8 vv;
            vv[0] = v0[0]; vv[1] = v0[1]; vv[2] = v0[2]; vv[3] = v0[3];
            vv[4] = v1[0]; vv[5] = v1[1]; vv[6] = v1[2]; vv[7] = v1[3];
            vf[fh] = vv;
        }
    };

    auto compute = [&](int kv0, int q0, const short8 (&qf)[2][2],
                       const short8 (&kf)[2][2], const short8 (&vf)[4],
                       f32x4 (&acc)[2][4], float (&m2)[2], float (&ls)[2]) {
#pragma unroll
        for (int sub = 0; sub < 2; ++sub) {
            f32x4 sv[2];
#pragma unroll
            for (int f = 0; f < 2; ++f) {
                f32x4 x = {};
                x = MFMA_16x16x32_BF16(kf[f][0], qf[sub][0], x);
                x = MFMA_16x16x32_BF16(kf[f][1], qf[sub][1], x);
                sv[f] = x;
            }
            const int q = q0 + 16 * sub + lr;
            float pvv[8], tmax = NEG_INF;
#pragma unroll
            for (int f = 0; f < 2; ++f)
#pragma unroll
                for (int r = 0; r < 4; ++r) {
                    int kp = kv0 + 16 * f + 4 * g + r;
                    float sc = sv[f][r] * SCALE2;
                    sc = (kp <= q) ? sc : NEG_INF;
                    pvv[4 * f + r] = sc;
                    tmax = fmaxf(tmax, sc);
                }
            tmax = fmaxf(tmax, __shfl_xor(tmax, 16));
            tmax = fmaxf(tmax, __shfl_xor(tmax, 32));
            float mnew = fmaxf(m2[sub], tmax);     // finite: kv0 <= q0 <= q always
            float alpha = exp2f(m2[sub] - mnew);
            float psum = 0.f;
            short8 pf;
#pragma unroll
            for (int e = 0; e < 8; ++e) {
                float pe = exp2f(pvv[e] - mnew);
                psum += pe;
                pf[e] = (short)f2bf(pe);
            }
            psum += __shfl_xor(psum, 16);
            psum += __shfl_xor(psum, 32);
            ls[sub] = ls[sub] * alpha + psum;
            m2[sub] = mnew;
#pragma unroll
            for (int fh = 0; fh < 4; ++fh) {
                acc[sub][fh][0] *= alpha; acc[sub][fh][1] *= alpha;
                acc[sub][fh][2] *= alpha; acc[sub][fh][3] *= alpha;
                acc[sub][fh] = MFMA_16x16x32_BF16(vf[fh], pf, acc[sub][fh]);
            }
        }
    };

    auto kvof = [&](int s) { return (s < nhi ? s : s - nhi) * 32; };

    short8 kf[2][2], vf[4];
    loadKV(kvof(s0), kf, vf);
    for (int s = s0; s < s1; ++s) {
        short8 kf2[2][2], vf2[4];
        if (s + 1 < s1) loadKV(kvof(s + 1), kf2, vf2);
        const int kv0 = kvof(s);
        if (s < nhi) compute(kv0, q0h, qfH, kf, vf, accH, mH, lH);
        else         compute(kv0, q0l, qfL, kf, vf, accL, mL, lL);
#pragma unroll
        for (int f = 0; f < 2; ++f) {
            kf[f][0] = kf2[f][0]; kf[f][1] = kf2[f][1];
        }
#pragma unroll
        for (int fh = 0; fh < 4; ++fh) vf[fh] = vf2[fh];
    }

    // ---- write partials to LDS ----
#pragma unroll
    for (int bnd = 0; bnd < 2; ++bnd) {
        const f32x4 (&acc)[2][4] = bnd ? accL : accH;
        const float (&m2)[2] = bnd ? mL : mH;
        const float (&ls)[2] = bnd ? lL : lH;
        const int slot = bnd * 8 + w;
#pragma unroll
        for (int sub = 0; sub < 2; ++sub) {
#pragma unroll
            for (int fh = 0; fh < 4; ++fh)
                *(f32x4*)&Pacc[slot][16 * sub + lr][16 * fh + 4 * g] = acc[sub][fh];
            if (g == 0) {
                Pml[0][slot][16 * sub + lr] = m2[sub];
                Pml[1][slot][16 * sub + lr] = ls[sub];
            }
        }
    }
    __syncthreads();

    // ---- combine: 512 thr -> 2 bands x 32 q x 8 h-groups ----
    {
        const int tb = t >> 8, t2 = t & 255;
        const int qq = t2 & 31, hb = (t2 >> 5) * 8;
        float mw[8], M = NEG_INF;
#pragma unroll
        for (int wv = 0; wv < 8; ++wv) {
            mw[wv] = Pml[0][tb * 8 + wv][qq];
            M = fmaxf(M, mw[wv]);
        }
        float wgt[8], L = 0.f;
#pragma unroll
        for (int wv = 0; wv < 8; ++wv) {
            wgt[wv] = exp2f(mw[wv] - M);           // exp2(-inf)=0 for idle waves
            L += wgt[wv] * Pml[1][tb * 8 + wv][qq];
        }
        f32x4 o0 = {}, o1 = {};
#pragma unroll
        for (int wv = 0; wv < 8; ++wv) {
            f32x4 a0 = *(const f32x4*)&Pacc[tb * 8 + wv][qq][hb];
            f32x4 a1 = *(const f32x4*)&Pacc[tb * 8 + wv][qq][hb + 4];
            o0 += wgt[wv] * a0;
            o1 += wgt[wv] * a1;
        }
        const float invL = 1.f / L;
        o0 *= invL; o1 *= invL;
        const int q0 = tb ? q0l : q0h;
        float* op = out + (rowbase + q0 + qq) * 64 + hb;
        *(f32x4*)op = o0;
        *(f32x4*)(op + 4) = o1;
    }
}

// ---------------------------------------------------------------------------
extern "C" void kernel_launch(void* const* d_in, const int* in_sizes, int n_in,
                              void* d_out, int out_size, void* d_ws, size_t ws_size,
                              hipStream_t stream) {
    const float* X  = (const float*)d_in[0];
    const float* Wk = (const float*)d_in[1];
    const float* Wq = (const float*)d_in[2];
    const float* Wv = (const float*)d_in[3];

    unsigned short* Wt  = (unsigned short*)d_ws;       // 192*1024 bf16
    unsigned short* Kb  = Wt + 192 * 1024;             // [16384][64] bf16
    unsigned short* Qb  = Kb + 16384 * 64;             // [16384][64] bf16
    unsigned short* Vtg = Qb + 16384 * 64;             // [8][64][2048] bf16 (V^T)
    float* out = (float*)d_out;

    wconv_kernel<<<dim3(192), dim3(256), 0, stream>>>(Wk, Wq, Wv, Wt);
    proj_kernel<<<dim3(2, 1024), dim3(64), 0, stream>>>(X, Wt, Kb, Qb, Vtg);
    attn_kernel<<<dim3(32, 8), dim3(512), 0, stream>>>(Kb, Qb, Vtg, out);
}

// Round 5
// 58.835 us; speedup vs baseline: 1.6722x; 1.6722x over previous
//
#include <hip/hip_runtime.h>

typedef __attribute__((ext_vector_type(8))) short short8;
typedef __attribute__((ext_vector_type(4))) short short4v;
typedef __attribute__((ext_vector_type(4))) float f32x4;

#define MFMA_16x16x32_BF16(A, B, C) __builtin_amdgcn_mfma_f32_16x16x32_bf16(A, B, C, 0, 0, 0)

// float -> bf16 bits, round-to-nearest-even (inputs always finite here)
__device__ __forceinline__ unsigned short f2bf(float x) {
    unsigned int u = __builtin_bit_cast(unsigned int, x);
    u = (u + 0x7FFFu + ((u >> 16) & 1u)) >> 16;
    return (unsigned short)u;
}

// ---------------------------------------------------------------------------
// Kernel 1: pack Wk|Wq|Wv (fp32 [1024][64]) -> Wt bf16 [192][1024] transposed,
// with the proj LDS bank-swizzle PRE-BAKED: within each 64-k tile, 8-short
// chunk c holds logical chunk c ^ (n&7).  (G21: global_load_lds writes LDS
// linearly, so the conflict-free permutation must come from the source.)
// ---------------------------------------------------------------------------
__global__ __launch_bounds__(256) void wconv_kernel(const float* __restrict__ Wk,
                                                    const float* __restrict__ Wq,
                                                    const float* __restrict__ Wv,
                                                    unsigned short* __restrict__ Wt) {
    const int n = blockIdx.x;                       // 0..191
    const float* W = (n < 64) ? Wk : (n < 128) ? Wq : Wv;
    const int col = n & 63;
    const int sw = (n & 7) << 3;
    for (int k = threadIdx.x; k < 1024; k += 256) {
        const int kd = (k & ~56) | ((k ^ sw) & 56);   // XOR chunk bits 3..5
        Wt[(size_t)n * 1024 + kd] = f2bf(W[(size_t)k * 64 + col]);
    }
}

// ---------------------------------------------------------------------------
// Kernel 2: QKV projection GEMM, m97-structure.
// BM=32, BN=192 (all of K|Q|V), BK=64.  256 thr = 4 waves: wave (wr=w>>1)
// owns 16 rows, (wc=w&1) owns a 96-col half.  Grid 512 = 2 blocks/CU so
// cross-block TLP hides the barrier vmcnt drain (round-2's missing piece).
// W staged LDS-linear via global_load_lds width=16 (source pre-swizzled by
// wconv; frag reads XOR by row&7 -> conflict-free).  A staged via regs
// (fp32->bf16 convert) into padded rows; next-tile A loads issued after
// barrier 2, dependent convert after the MFMAs (latency under compute).
// Outputs: Kb/Qb row-major [16384][64]; V transposed Vtg[b][64][2048].
// ---------------------------------------------------------------------------
__global__ __launch_bounds__(256) void proj_kernel(const float* __restrict__ X,
                                                   const unsigned short* __restrict__ Wt,
                                                   unsigned short* __restrict__ Kb,
                                                   unsigned short* __restrict__ Qb,
                                                   unsigned short* __restrict__ Vtg) {
    __shared__ __attribute__((aligned(16))) unsigned short Al[32 * 72];   // pad 64->72
    __shared__ __attribute__((aligned(16))) unsigned short Wl[192 * 64];  // linear (glds)
    const int t = threadIdx.x;
    const int w = t >> 6, lane = t & 63, lr = lane & 15, g = lane >> 4;
    const int wr = w >> 1, wc = w & 1;
    const int r0 = blockIdx.x * 32;

    f32x4 acc[6] = {};

    // A staging coords: row = t>>3 (0..31), chunk j = t&7 (8 floats)
    const int ar = t >> 3, aj = t & 7;
    const float* xsrc = X + (size_t)(r0 + ar) * 1024 + aj * 8;

    float4 a0 = *(const float4*)xsrc;
    float4 a1 = *(const float4*)(xsrc + 4);
    uint4 aw;
    aw.x = (unsigned)f2bf(a0.x) | ((unsigned)f2bf(a0.y) << 16);
    aw.y = (unsigned)f2bf(a0.z) | ((unsigned)f2bf(a0.w) << 16);
    aw.z = (unsigned)f2bf(a1.x) | ((unsigned)f2bf(a1.y) << 16);
    aw.w = (unsigned)f2bf(a1.z) | ((unsigned)f2bf(a1.w) << 16);

    for (int k0 = 0; k0 < 1024; k0 += 64) {
        __syncthreads();                          // (1) prev compute done with LDS
        // ---- W tile: 1536 16B chunks, direct global->LDS, linear dest ----
#pragma unroll
        for (int i = 0; i < 6; ++i) {
            const int q = t + 256 * i;
            const unsigned short* src = Wt + (size_t)(q >> 3) * 1024 + k0 + (q & 7) * 8;
            __builtin_amdgcn_global_load_lds((const __attribute__((address_space(1))) void*)src,
                                             (__attribute__((address_space(3))) void*)&Wl[q * 8],
                                             16, 0, 0);
        }
        // ---- A tile: converted regs -> padded LDS ----
        *(uint4*)&Al[ar * 72 + aj * 8] = aw;
        __syncthreads();                          // (2) drains vmcnt+lgkm: tiles ready

        const bool more = (k0 + 64) < 1024;
        if (more) {                               // issue next A loads (hide under MFMAs)
            a0 = *(const float4*)(xsrc + k0 + 64);
            a1 = *(const float4*)(xsrc + k0 + 68);
        }

        // ---- compute ----
        short8 af[2];
        af[0] = *(const short8*)&Al[(16 * wr + lr) * 72 + 8 * g];
        af[1] = *(const short8*)&Al[(16 * wr + lr) * 72 + 32 + 8 * g];
#pragma unroll
        for (int c = 0; c < 6; ++c) {
            const int row = 96 * wc + 16 * c + lr;
#pragma unroll
            for (int sub = 0; sub < 2; ++sub) {
                const int cs = (4 * sub + g) ^ (lr & 7);     // un-swizzle
                short8 wf = *(const short8*)&Wl[row * 64 + cs * 8];
                acc[c] = MFMA_16x16x32_BF16(af[sub], wf, acc[c]);
            }
        }

        if (more) {                               // dependent convert AFTER compute
            aw.x = (unsigned)f2bf(a0.x) | ((unsigned)f2bf(a0.y) << 16);
            aw.y = (unsigned)f2bf(a0.z) | ((unsigned)f2bf(a0.w) << 16);
            aw.z = (unsigned)f2bf(a1.x) | ((unsigned)f2bf(a1.y) << 16);
            aw.w = (unsigned)f2bf(a1.z) | ((unsigned)f2bf(a1.w) << 16);
        }
    }

    // ---- epilogue: C/D layout col = lane&15 (W-col), row = 4*(lane>>4)+reg ----
    const int bb = r0 >> 11;                      // batch
    const int sb0 = (r0 & 2047) + 16 * wr;        // s within batch (+4g+r)
    const int row = r0 + 16 * wr + 4 * g;
#pragma unroll
    for (int c = 0; c < 6; ++c) {
        const int n = 96 * wc + 16 * c;           // + lr
        if (n < 64) {
#pragma unroll
            for (int r = 0; r < 4; ++r)
                Kb[(size_t)(row + r) * 64 + n + lr] = f2bf(acc[c][r]);
        } else if (n < 128) {
#pragma unroll
            for (int r = 0; r < 4; ++r)
                Qb[(size_t)(row + r) * 64 + (n - 64) + lr] = f2bf(acc[c][r]);
        } else {
            const int h = n - 128 + lr;
            uint2 e;
            e.x = (unsigned)f2bf(acc[c][0]) | ((unsigned)f2bf(acc[c][1]) << 16);
            e.y = (unsigned)f2bf(acc[c][2]) | ((unsigned)f2bf(acc[c][3]) << 16);
            *(uint2*)(Vtg + (size_t)bb * 64 * 2048 + (size_t)h * 2048 + sb0 + 4 * g) = e;
        }
    }
}

// ---------------------------------------------------------------------------
// Kernel 3: causal flash attention, band-pair blocks (round-2 version, the
// measured-best).  Block = bands {63-p (hi), p (lo)} of 32 q-rows each ->
// exactly 65 kv-steps per block.  8 waves split the 65 steps contiguously;
// K and V^T fragments load DIRECTLY from global (L2-resident) -> no LDS, no
// barriers in the main loop.  Partials merged in LDS at the end.
// ---------------------------------------------------------------------------
__global__ __launch_bounds__(512, 2) void attn_kernel(const unsigned short* __restrict__ Kb,
                                                      const unsigned short* __restrict__ Qb,
                                                      const unsigned short* __restrict__ Vtg,
                                                      float* __restrict__ out) {
    __shared__ __attribute__((aligned(16))) float Pacc[16][32][68];  // [slot][q][h] pad 68
    __shared__ float Pml[2][16][32];                                 // m / l per slot,q

    const int t = threadIdx.x;
    const int w = t >> 6, lane = t & 63;
    const int lr = lane & 15, g = lane >> 4;
    const int p = blockIdx.x, b = blockIdx.y;
    const int nhi = 64 - p;                      // steps for hi band
    const int q0h = (63 - p) * 32, q0l = p * 32;
    const size_t rowbase = (size_t)b * 2048;
    const size_t vbase = (size_t)b * 64 * 2048;
    const float NEG_INF = -__builtin_inff();
    const float SCALE2 = 0.03125f * 1.4426950408889634f;   // d^-0.5 * log2(e)

    // Q fragments (B-operand): [sub][hh]
    short8 qfH[2][2], qfL[2][2];
#pragma unroll
    for (int sub = 0; sub < 2; ++sub)
#pragma unroll
        for (int hh = 0; hh < 2; ++hh) {
            qfH[sub][hh] = *(const short8*)(Qb + (rowbase + q0h + 16 * sub + lr) * 64 + 32 * hh + 8 * g);
            qfL[sub][hh] = *(const short8*)(Qb + (rowbase + q0l + 16 * sub + lr) * 64 + 32 * hh + 8 * g);
        }

    f32x4 accH[2][4] = {}, accL[2][4] = {};
    float mH[2] = {NEG_INF, NEG_INF}, mL[2] = {NEG_INF, NEG_INF};
    float lH[2] = {0.f, 0.f}, lL[2] = {0.f, 0.f};

    const int s0 = (w * 65) >> 3, s1 = ((w + 1) * 65) >> 3;

    auto step = [&](int kv0, int q0, const short8 (&qf)[2][2],
                    f32x4 (&acc)[2][4], float (&m2)[2], float (&ls)[2]) {
        // K A-frags direct from global: row kv0+16f+lr, cols 32hh+8g (16B)
        short8 kf[2][2];
#pragma unroll
        for (int f = 0; f < 2; ++f)
#pragma unroll
            for (int hh = 0; hh < 2; ++hh)
                kf[f][hh] = *(const short8*)(Kb + (rowbase + kv0 + 16 * f + lr) * 64 + 32 * hh + 8 * g);
        // V^T A-frags direct from Vtg: row h=16fh+lr, kv cols 4g.. / 16+4g..
        short8 vf[4];
#pragma unroll
        for (int fh = 0; fh < 4; ++fh) {
            const unsigned short* vp = Vtg + vbase + (size_t)(16 * fh + lr) * 2048 + kv0 + 4 * g;
            short4v v0 = *(const short4v*)vp;
            short4v v1 = *(const short4v*)(vp + 16);
            short8 vv;
            vv[0] = v0[0]; vv[1] = v0[1]; vv[2] = v0[2]; vv[3] = v0[3];
            vv[4] = v1[0]; vv[5] = v1[1]; vv[6] = v1[2]; vv[7] = v1[3];
            vf[fh] = vv;
        }
#pragma unroll
        for (int sub = 0; sub < 2; ++sub) {
            f32x4 sv[2];
#pragma unroll
            for (int f = 0; f < 2; ++f) {
                f32x4 x = {};
                x = MFMA_16x16x32_BF16(kf[f][0], qf[sub][0], x);
                x = MFMA_16x16x32_BF16(kf[f][1], qf[sub][1], x);
                sv[f] = x;
            }
            const int q = q0 + 16 * sub + lr;
            float pvv[8], tmax = NEG_INF;
#pragma unroll
            for (int f = 0; f < 2; ++f)
#pragma unroll
                for (int r = 0; r < 4; ++r) {
                    int kp = kv0 + 16 * f + 4 * g + r;
                    float sc = sv[f][r] * SCALE2;
                    sc = (kp <= q) ? sc : NEG_INF;
                    pvv[4 * f + r] = sc;
                    tmax = fmaxf(tmax, sc);
                }
            tmax = fmaxf(tmax, __shfl_xor(tmax, 16));
            tmax = fmaxf(tmax, __shfl_xor(tmax, 32));
            float mnew = fmaxf(m2[sub], tmax);     // finite: kv0 <= q0 <= q always
            float alpha = exp2f(m2[sub] - mnew);
            float psum = 0.f;
            short8 pf;
#pragma unroll
            for (int e = 0; e < 8; ++e) {
                float pe = exp2f(pvv[e] - mnew);
                psum += pe;
                pf[e] = (short)f2bf(pe);
            }
            psum += __shfl_xor(psum, 16);
            psum += __shfl_xor(psum, 32);
            ls[sub] = ls[sub] * alpha + psum;
            m2[sub] = mnew;
#pragma unroll
            for (int fh = 0; fh < 4; ++fh) {
                acc[sub][fh][0] *= alpha; acc[sub][fh][1] *= alpha;
                acc[sub][fh][2] *= alpha; acc[sub][fh][3] *= alpha;
                acc[sub][fh] = MFMA_16x16x32_BF16(vf[fh], pf, acc[sub][fh]);
            }
        }
    };

    const int ehi = (s1 < nhi) ? s1 : nhi;
    for (int s = s0; s < ehi; ++s) step(s * 32, q0h, qfH, accH, mH, lH);
    const int slo = (s0 > nhi) ? s0 : nhi;
    for (int s = slo; s < s1; ++s) step((s - nhi) * 32, q0l, qfL, accL, mL, lL);

    // ---- write partials to LDS ----
#pragma unroll
    for (int bnd = 0; bnd < 2; ++bnd) {
        const f32x4 (&acc)[2][4] = bnd ? accL : accH;
        const float (&m2)[2] = bnd ? mL : mH;
        const float (&ls)[2] = bnd ? lL : lH;
        const int slot = bnd * 8 + w;
#pragma unroll
        for (int sub = 0; sub < 2; ++sub) {
#pragma unroll
            for (int fh = 0; fh < 4; ++fh)
                *(f32x4*)&Pacc[slot][16 * sub + lr][16 * fh + 4 * g] = acc[sub][fh];
            if (g == 0) {
                Pml[0][slot][16 * sub + lr] = m2[sub];
                Pml[1][slot][16 * sub + lr] = ls[sub];
            }
        }
    }
    __syncthreads();

    // ---- combine: 512 thr -> 2 bands x 32 q x 8 h-groups ----
    {
        const int tb = t >> 8, t2 = t & 255;
        const int qq = t2 & 31, hb = (t2 >> 5) * 8;
        float mw[8], M = NEG_INF;
#pragma unroll
        for (int wv = 0; wv < 8; ++wv) {
            mw[wv] = Pml[0][tb * 8 + wv][qq];
            M = fmaxf(M, mw[wv]);
        }
        float wgt[8], L = 0.f;
#pragma unroll
        for (int wv = 0; wv < 8; ++wv) {
            wgt[wv] = exp2f(mw[wv] - M);           // exp2(-inf)=0 for idle waves
            L += wgt[wv] * Pml[1][tb * 8 + wv][qq];
        }
        f32x4 o0 = {}, o1 = {};
#pragma unroll
        for (int wv = 0; wv < 8; ++wv) {
            f32x4 a0 = *(const f32x4*)&Pacc[tb * 8 + wv][qq][hb];
            f32x4 a1 = *(const f32x4*)&Pacc[tb * 8 + wv][qq][hb + 4];
            o0 += wgt[wv] * a0;
            o1 += wgt[wv] * a1;
        }
        const float invL = 1.f / L;
        o0 *= invL; o1 *= invL;
        const int q0 = tb ? q0l : q0h;
        float* op = out + (rowbase + q0 + qq) * 64 + hb;
        *(f32x4*)op = o0;
        *(f32x4*)(op + 4) = o1;
    }
}

// ---------------------------------------------------------------------------
extern "C" void kernel_launch(void* const* d_in, const int* in_sizes, int n_in,
                              void* d_out, int out_size, void* d_ws, size_t ws_size,
                              hipStream_t stream) {
    const float* X  = (const float*)d_in[0];
    const float* Wk = (const float*)d_in[1];
    const float* Wq = (const float*)d_in[2];
    const float* Wv = (const float*)d_in[3];

    unsigned short* Wt  = (unsigned short*)d_ws;       // 192*1024 bf16 (swizzled)
    unsigned short* Kb  = Wt + 192 * 1024;             // [16384][64] bf16
    unsigned short* Qb  = Kb + 16384 * 64;             // [16384][64] bf16
    unsigned short* Vtg = Qb + 16384 * 64;             // [8][64][2048] bf16 (V^T)
    float* out = (float*)d_out;

    wconv_kernel<<<dim3(192), dim3(256), 0, stream>>>(Wk, Wq, Wv, Wt);
    proj_kernel<<<dim3(512), dim3(256), 0, stream>>>(X, Wt, Kb, Qb, Vtg);
    attn_kernel<<<dim3(32, 8), dim3(512), 0, stream>>>(Kb, Qb, Vtg, out);
}